// Round 15
// baseline (165.302 us; speedup 1.0000x reference)
//
#include <hip/hip_runtime.h>
#include <hip/hip_fp16.h>

#define TPB 256
#define TPBP 1024        // k_place block (16 waves)
#define TPBS 512         // k_sort2 block
#define RNG 128          // nodes per range
#define RSH 7            // log2(RNG)
#define MAXC 1024        // max ranges supported by LDS hist (N <= 131072)
#define EPB 8192         // edges per block in place (chunk ~10.5 edges)
#define CAPR 4096        // per-range region capacity (mean ~2046, ~40 sigma)
#define CSH 12           // log2(CAPR)
#define DB 64            // degree bins for per-range rank sort

// ---------------------------------------------------------------------------
// GCN, fully commuted (aggregate only at width 16):
//   hsx = fp16(dinv*x) [N,16];  z = fp16((relu(dinv*agg@W1+b1)*dinv)@Wf) [N,16]
//   out = dinv*(z[n]+sum z[s]) + bf      (Wf = W2@WL, bf = b2@WL + bL)
// Build: fixed-capacity per-range regions (no global hist/scan):
//   place: LDS count -> one atomicAdd(&gcur[c],v) chunk reservation per
//          (block,range) -> chunked packed writes into gbuf[c*4096+..]
//   sort2: region -> LDS elist -> per-node sort -> bucketS region,
//          pack[n]=(exoff<<16)|deg, fp16 hsx, AND nid[slot] = per-range
//          degree-ranked node permutation (waves see uniform degrees ->
//          no exec-mask divergence in the gather loops).
// Aggregation: nodes-in-lane transpose gather over nid slots, packed CSR.
// Replay-stable: per-node sums have fixed shape regardless of perm order;
// no fp atomics (R9 tripwire lesson).
// ---------------------------------------------------------------------------

__device__ inline void acc4(float a[4], uint2 u) {
    __half2 h0 = *(__half2*)&u.x, h1 = *(__half2*)&u.y;
    float2 f0 = __half22float2(h0), f1 = __half22float2(h1);
    a[0] += f0.x; a[1] += f0.y; a[2] += f1.x; a[3] += f1.y;
}

// Wf/bf fusion + gcur zeroing (replaces memset dispatch)
__global__ void k_wfuse(const float* __restrict__ W2, const float* __restrict__ WL,
                        const float* __restrict__ b2, const float* __restrict__ bL,
                        float* __restrict__ Wf, float* __restrict__ bf,
                        int* __restrict__ gcur, int C) {
    int gid = blockIdx.x * TPB + threadIdx.x;     // 4 blocks * 256 = 1024
    for (int i = gid; i < C; i += 4 * TPB) gcur[i] = 0;
    int k = gid >> 4, o = gid & 15;
    if (k < 64) {
        float s = 0.f;
#pragma unroll 8
        for (int j = 0; j < 128; j++) s += W2[k * 128 + j] * WL[j * 16 + o];
        Wf[gid] = s;
    }
    if (gid < 16) {
        float s = bL[gid];
        for (int j = 0; j < 128; j++) s += b2[j] * WL[j * 16 + gid];
        bf[gid] = s;
    }
}

// place packed (src<<7 | dst&127) into per-range fixed regions; chunk reservation
__global__ __launch_bounds__(TPBP) void
k_place(const int* __restrict__ ei, int* __restrict__ gcur,
        unsigned* __restrict__ gbuf, int E, int C) {
    __shared__ int h[MAXC];
    int t = threadIdx.x, b = blockIdx.x;
    for (int c = t; c < C; c += TPBP) h[c] = 0;
    __syncthreads();
    const int4* s4p = (const int4*)ei;
    const int4* d4p = (const int4*)(ei + E);
    int nq = E >> 2;
    int qbase = b * (EPB / 4);
#pragma unroll
    for (int it = 0; it < EPB / (4 * TPBP); it++) {  // pass 1: count
        int q = qbase + it * TPBP + t;
        if (q < nq) {
            int4 d = d4p[q];
            atomicAdd(&h[d.x >> RSH], 1);
            atomicAdd(&h[d.y >> RSH], 1);
            atomicAdd(&h[d.z >> RSH], 1);
            atomicAdd(&h[d.w >> RSH], 1);
        }
    }
    __syncthreads();
    for (int c = t; c < C; c += TPBP) {           // reserve chunk per range
        int v = h[c];
        if (v) h[c] = (c << CSH) + atomicAdd(&gcur[c], v);   // absolute cursor
    }
    __syncthreads();
#pragma unroll
    for (int it = 0; it < EPB / (4 * TPBP); it++) {  // pass 2: chunked place
        int q = qbase + it * TPBP + t;
        if (q < nq) {
            int4 s = s4p[q];
            int4 d = d4p[q];
            int c0 = d.x >> RSH, c1 = d.y >> RSH, c2 = d.z >> RSH, c3 = d.w >> RSH;
            int p0 = atomicAdd(&h[c0], 1);
            if (p0 < ((c0 + 1) << CSH))
                gbuf[p0] = ((unsigned)s.x << RSH) | (unsigned)(d.x & (RNG - 1));
            int p1 = atomicAdd(&h[c1], 1);
            if (p1 < ((c1 + 1) << CSH))
                gbuf[p1] = ((unsigned)s.y << RSH) | (unsigned)(d.y & (RNG - 1));
            int p2 = atomicAdd(&h[c2], 1);
            if (p2 < ((c2 + 1) << CSH))
                gbuf[p2] = ((unsigned)s.z << RSH) | (unsigned)(d.z & (RNG - 1));
            int p3 = atomicAdd(&h[c3], 1);
            if (p3 < ((c3 + 1) << CSH))
                gbuf[p3] = ((unsigned)s.w << RSH) | (unsigned)(d.w & (RNG - 1));
        }
    }
}

// per-range node-sort (via LDS elist) -> bucketS region + packed CSR + hsx
// + degree-ranked permutation nid[r*128 + rank] = node (or -1)
__global__ __launch_bounds__(TPBS) void
k_sort2(const unsigned* __restrict__ gbuf, const int* __restrict__ gcur,
        const float* __restrict__ x,
        int* __restrict__ bucketS, unsigned* __restrict__ pack,
        int* __restrict__ nid, __half2* __restrict__ hsx, int N, int C) {
    __shared__ unsigned elist[CAPR];              // 16 KiB
    __shared__ int cnt[RNG];
    __shared__ int offs[RNG];
    __shared__ int cur[RNG];
    __shared__ float sdi[RNG];
    __shared__ int dcur[DB];
    int t = threadIdx.x, r = blockIdx.x;
    if (t < RNG) cnt[t] = 0;
    if (t < DB) dcur[t] = 0;
    __syncthreads();
    int m = min(gcur[r], CAPR);
    const unsigned* src = gbuf + ((size_t)r << CSH);
    for (int i = t; i < m; i += TPBS) {           // single global read of region
        unsigned p = src[i];
        elist[i] = p;
        atomicAdd(&cnt[p & (RNG - 1)], 1);
    }
    __syncthreads();
    if (t < RNG) offs[t] = cnt[t];
    // degree-bin histogram (only valid nodes)
    if (t < RNG && (r * RNG + t) < N) atomicAdd(&dcur[min(cnt[t], DB - 1)], 1);
    __syncthreads();
    for (int off = 1; off < RNG; off <<= 1) {     // scan of edge counts
        int v = 0;
        if (t < RNG && t >= off) v = offs[t - off];
        __syncthreads();
        if (t < RNG) offs[t] += v;
        __syncthreads();
    }
    // exclusive scan of degree bins (DB=64, single wave 0 does it serially-ish)
    __shared__ int dbase[DB];
    if (t < DB) dbase[t] = dcur[t];
    __syncthreads();
    for (int off = 1; off < DB; off <<= 1) {
        int v = 0;
        if (t < DB && t >= off) v = dbase[t - off];
        __syncthreads();
        if (t < DB) dbase[t] += v;
        __syncthreads();
    }
    if (t < DB) dcur[t] = dbase[t] - ((t < DB) ? 0 : 0);   // inclusive
    __syncthreads();
    if (t < DB) dcur[t] = dbase[t];               // will use as post-increment from exclusive
    __syncthreads();
    if (t < DB) {
        // convert inclusive->exclusive
        int incl = dbase[t];
        int cntb = (t == 0) ? incl : incl - dbase[t - 1];
        dcur[t] = incl - cntb;
    }
    if (t < RNG) nid[(r << RSH) + t] = -1;        // init slots
    __syncthreads();
    if (t < RNG) {
        int ex = offs[t] - cnt[t];                // exclusive edge offset
        cur[t] = ex;
        sdi[t] = rsqrtf((float)cnt[t] + 1.0f);    // +1 self-loop
        int n = r * RNG + t;
        if (n < N) {
            pack[n] = ((unsigned)ex << 16) | (unsigned)cnt[t];
            int rank = atomicAdd(&dcur[min(cnt[t], DB - 1)], 1);
            nid[(r << RSH) + rank] = n;           // degree-ranked slot
        }
    }
    __syncthreads();
    int rbase = r << CSH;
    for (int i = t; i < m; i += TPBS) {
        unsigned p = elist[i];
        int pos = rbase + atomicAdd(&cur[p & (RNG - 1)], 1);
        bucketS[pos] = (int)(p >> RSH);
    }
    // fused: hsx[n][:] = fp16(dinv[n] * x[n][:]) — 128 nodes x 8 half2
    for (int idx = t; idx < RNG * 8; idx += TPBS) {
        int ln = idx >> 3, f2 = idx & 7;
        int n = r * RNG + ln;
        if (n < N) {
            float2 xv = ((const float2*)x)[(size_t)n * 8 + f2];
            float dn = sdi[ln];
            hsx[(size_t)n * 8 + f2] = __floats2half2_rn(xv.x * dn, xv.y * dn);
        }
    }
}

// layer 1 + projection: nodes-in-lane gather over degree-ranked slots
__global__ void k_l1f(const int* __restrict__ bucketS, const unsigned* __restrict__ pack,
                      const int* __restrict__ nid,
                      const uint2* __restrict__ hsx, const float* __restrict__ W1,
                      const float* __restrict__ b1, const float* __restrict__ Wf,
                      __half2* __restrict__ z, int SLOTS) {
    __shared__ __align__(16) float agg[4][16][16];   // [wave][node][feat]
    __shared__ __align__(16) float vrow[4][64];
    int t = threadIdx.x, wid = t >> 6, lane = t & 63;
    int part = lane >> 4, o = lane & 15;
    float w1c[16], wfc[16];
#pragma unroll
    for (int k = 0; k < 16; k++) w1c[k] = W1[k * 64 + lane];
#pragma unroll
    for (int j = 0; j < 16; j++) wfc[j] = Wf[(part * 16 + j) * 16 + o];
    float b1v = b1[lane];
    int slotG = (blockIdx.x * 4 + wid) * 16;      // 16 slots per wave
    int n4 = lane >> 2, q = lane & 3;
    int slot = slotG + n4;
    int n = (slot < SLOTS) ? nid[slot] : -1;      // true node id (or -1)
    bool valid = n >= 0;
    int base = 0, d = 0;
    if (valid) {
        unsigned p = pack[n];
        base = ((n >> RSH) << CSH) + (int)(p >> 16);
        d = (int)(p & 0xFFFF);
    }
    float a[4] = {0.f, 0.f, 0.f, 0.f};
    if (valid) acc4(a, hsx[(size_t)n * 4 + q]);   // self-loop
    int k = 0;
    for (; k + 1 < d; k += 2) {                   // uniform degrees -> full masks
        int s0 = bucketS[base + k];
        int s1 = bucketS[base + k + 1];
        uint2 u0 = hsx[(size_t)s0 * 4 + q];
        uint2 u1 = hsx[(size_t)s1 * 4 + q];
        acc4(a, u0);
        acc4(a, u1);
    }
    if (k < d) acc4(a, hsx[(size_t)bucketS[base + k] * 4 + q]);
    *(float4*)&agg[wid][n4][q * 4] = make_float4(a[0], a[1], a[2], a[3]);
    // epilogue: 16 nodes batched; agg/vrow same-wave LDS roundtrips (b128)
    const float4* avp = (const float4*)agg[wid];
    const float4* vrp = (const float4*)vrow[wid];
#pragma unroll 4
    for (int nn = 0; nn < 16; nn++) {
        int node = __shfl(n, nn * 4);             // wave-uniform
        if (node < 0) continue;
        float dn = rsqrtf((float)__shfl(d, nn * 4) + 1.0f);
        float4 A0 = avp[nn * 4 + 0], A1 = avp[nn * 4 + 1];
        float4 A2 = avp[nn * 4 + 2], A3 = avp[nn * 4 + 3];
        float av[16] = {A0.x, A0.y, A0.z, A0.w, A1.x, A1.y, A1.z, A1.w,
                        A2.x, A2.y, A2.z, A2.w, A3.x, A3.y, A3.z, A3.w};
        float v = 0.f;
#pragma unroll
        for (int kk = 0; kk < 16; kk++) v += av[kk] * w1c[kk];
        v = fmaxf(dn * v + b1v, 0.f) * dn;        // lane j holds v_j
        vrow[wid][lane] = v;
        float4 V0 = vrp[part * 4 + 0], V1 = vrp[part * 4 + 1];
        float4 V2 = vrp[part * 4 + 2], V3 = vrp[part * 4 + 3];
        float vv[16] = {V0.x, V0.y, V0.z, V0.w, V1.x, V1.y, V1.z, V1.w,
                        V2.x, V2.y, V2.z, V2.w, V3.x, V3.y, V3.z, V3.w};
        float s = 0.f;
#pragma unroll
        for (int j = 0; j < 16; j++) s += vv[j] * wfc[j];
        s += __shfl_xor(s, 16);
        s += __shfl_xor(s, 32);                   // all lanes: z_o, o=lane&15
        float pv = __shfl(s, lane | 1);
        if (part == 0 && !(lane & 1))
            z[(size_t)node * 8 + (o >> 1)] = __floats2half2_rn(s, pv);
    }
}

// layer 2 aggregation of z + bias over degree-ranked slots
__global__ void k_l3(const int* __restrict__ bucketS, const unsigned* __restrict__ pack,
                     const int* __restrict__ nid,
                     const uint2* __restrict__ z, const float* __restrict__ bfv,
                     float* __restrict__ out, int SLOTS) {
    int t = threadIdx.x, wid = t >> 6, lane = t & 63;
    int n4 = lane >> 2, q = lane & 3;
    int slot = (blockIdx.x * 4 + wid) * 16 + n4;
    if (slot >= SLOTS) return;
    int n = nid[slot];
    if (n < 0) return;
    float4 bq = ((const float4*)bfv)[q];
    unsigned p = pack[n];
    int base = ((n >> RSH) << CSH) + (int)(p >> 16);
    int d = (int)(p & 0xFFFF);
    float a[4] = {0.f, 0.f, 0.f, 0.f};
    acc4(a, z[(size_t)n * 4 + q]);                // self-loop
    int k = 0;
    for (; k + 1 < d; k += 2) {
        int s0 = bucketS[base + k];
        int s1 = bucketS[base + k + 1];
        uint2 u0 = z[(size_t)s0 * 4 + q];
        uint2 u1 = z[(size_t)s1 * 4 + q];
        acc4(a, u0);
        acc4(a, u1);
    }
    if (k < d) acc4(a, z[(size_t)bucketS[base + k] * 4 + q]);
    float dn = rsqrtf((float)d + 1.0f);
    float4 r;
    r.x = dn * a[0] + bq.x;
    r.y = dn * a[1] + bq.y;
    r.z = dn * a[2] + bq.z;
    r.w = dn * a[3] + bq.w;
    ((float4*)out)[(size_t)n * 4 + q] = r;        // 64B line-aligned per node
}

extern "C" void kernel_launch(void* const* d_in, const int* in_sizes, int n_in,
                              void* d_out, int out_size, void* d_ws, size_t ws_size,
                              hipStream_t stream) {
    const float* x  = (const float*)d_in[0];
    const int*   ei = (const int*)d_in[1];
    const float* W1 = (const float*)d_in[2];
    const float* b1 = (const float*)d_in[3];
    const float* W2 = (const float*)d_in[4];
    const float* b2 = (const float*)d_in[5];
    const float* WL = (const float*)d_in[6];
    const float* bL = (const float*)d_in[7];
    float* out = (float*)d_out;

    const int N  = in_sizes[0] / 16;       // 100000
    const int E  = in_sizes[1] / 2;        // 1600000
    const int C  = (N + RNG - 1) >> RSH;   // 782 ranges
    const int NB = (E + EPB - 1) / EPB;    // 196 place blocks
    const int SLOTS = C << RSH;            // 100096 degree-ranked slots

    // ws ints: gbuf[C*CAPR] | bucketS[C*CAPR] | gcur[C] | pack[N] | nid[SLOTS] | pad
    //    then: Wf[1024] f32 | bf[16] | pad16B | hsx[8N] half2 | z[8N] half2
    int* wsi        = (int*)d_ws;
    unsigned* gbuf  = (unsigned*)wsi;
    int* bucketS    = wsi + ((size_t)C << CSH);
    int* gcur       = bucketS + ((size_t)C << CSH);
    unsigned* pack  = (unsigned*)(gcur + C);
    int* nid        = (int*)(pack + N);
    size_t off      = ((size_t)C << (CSH + 1)) + C + N + SLOTS;
    off = (off + 3) & ~(size_t)3;
    float* Wf    = (float*)(wsi + off);
    float* bf    = Wf + 1024;
    off = off + 1024 + 16;
    off = (off + 3) & ~(size_t)3;                 // 16B-align fp16 section
    __half2* hsx = (__half2*)(wsi + off);         // 8N half2
    __half2* z   = (__half2*)(wsi + off + (size_t)8 * N);

    // weight fusion + gcur zeroing (precedes k_place in stream order)
    k_wfuse<<<4, TPB, 0, stream>>>(W2, WL, b2, bL, Wf, bf, gcur, C);

    // ---- single-pass chunked placement into per-range regions ----
    k_place<<<NB, TPBP, 0, stream>>>(ei, gcur, gbuf, E, C);

    // ---- per-range node sort -> region CSR + pack + nid + fp16 hsx ----
    k_sort2<<<C, TPBS, 0, stream>>>(gbuf, gcur, x, bucketS, pack, nid, hsx, N, C);

    // ---- layer 1 + projection -> z fp16 [N,16] ----
    const int NBLK = (SLOTS + 63) / 64;           // 64 slots per block (16/wave)
    k_l1f<<<NBLK, TPB, 0, stream>>>(bucketS, pack, nid, (const uint2*)hsx, W1, b1, Wf, z, SLOTS);

    // ---- layer 2 aggregation + bias -> out ----
    k_l3<<<NBLK, TPB, 0, stream>>>(bucketS, pack, nid, (const uint2*)z, bf, out, SLOTS);
}

// Round 16
// 149.679 us; speedup vs baseline: 1.1044x; 1.1044x over previous
//
#include <hip/hip_runtime.h>
#include <hip/hip_fp16.h>

#define TPB 256
#define TPBP 1024        // k_place block (16 waves)
#define TPBS 512         // k_sort2 block
#define RNG 128          // nodes per range
#define RSH 7            // log2(RNG)
#define MAXC 1024        // max ranges supported by LDS hist (N <= 131072)
#define EPB 8192         // edges per block in place (chunk ~10.5 edges)
#define CAPR 4096        // per-range region capacity (mean ~2046, ~40 sigma)
#define CSH 12           // log2(CAPR)

// ---------------------------------------------------------------------------
// GCN, fully commuted (aggregate only at width 16):
//   hsx = fp16(dinv*x) [N,16];  z = fp16((relu(dinv*agg@W1+b1)*dinv)@Wf) [N,16]
//   out = dinv*(z[n]+sum z[s]) + bf      (Wf = W2@WL, bf = b2@WL + bL)
// Build: fixed-capacity per-range regions (no global hist/scan):
//   place: LDS count -> one atomicAdd(&gcur[c],v) chunk reservation per
//          (block,range) -> chunked packed writes into gbuf[c*4096+..];
//          extra block NB computes Wf/bf (replaces the k_wfuse dispatch).
//   sort2: region -> LDS elist -> per-node sort -> bucketS region,
//          pack[n]=(exoff<<16)|deg, fp16 hsx. dinv recomputed from deg later.
// Aggregation: nodes-in-lane transpose gather (R12/R14-proven), packed CSR.
// Replay-stable: fixed summation shape, no fp atomics (R9 tripwire lesson).
// R15 degree-ranked permutation REVERTED: divergence win < scatter-write loss.
// ---------------------------------------------------------------------------

__device__ inline void acc4(float a[4], uint2 u) {
    __half2 h0 = *(__half2*)&u.x, h1 = *(__half2*)&u.y;
    float2 f0 = __half22float2(h0), f1 = __half22float2(h1);
    a[0] += f0.x; a[1] += f0.y; a[2] += f1.x; a[3] += f1.y;
}

// place packed (src<<7 | dst&127) into per-range fixed regions; chunk
// reservation. Block NB (extra) instead computes Wf = W2@WL, bf = b2@WL + bL.
__global__ __launch_bounds__(TPBP) void
k_place(const int* __restrict__ ei, int* __restrict__ gcur,
        unsigned* __restrict__ gbuf,
        const float* __restrict__ W2, const float* __restrict__ WL,
        const float* __restrict__ b2, const float* __restrict__ bL,
        float* __restrict__ Wf, float* __restrict__ bf,
        int E, int C, int NB) {
    int t = threadIdx.x, b = blockIdx.x;
    if (b == NB) {                                 // fused weight-prep block
        int k = t >> 4, o = t & 15;                // t in [0,1024) = 64*16
        if (k < 64) {
            float s = 0.f;
#pragma unroll 8
            for (int j = 0; j < 128; j++) s += W2[k * 128 + j] * WL[j * 16 + o];
            Wf[t] = s;
        }
        if (t < 16) {
            float s = bL[t];
            for (int j = 0; j < 128; j++) s += b2[j] * WL[j * 16 + t];
            bf[t] = s;
        }
        return;
    }
    __shared__ int h[MAXC];
    for (int c = t; c < C; c += TPBP) h[c] = 0;
    __syncthreads();
    const int4* s4p = (const int4*)ei;
    const int4* d4p = (const int4*)(ei + E);
    int nq = E >> 2;
    int qbase = b * (EPB / 4);
#pragma unroll
    for (int it = 0; it < EPB / (4 * TPBP); it++) {  // pass 1: count
        int q = qbase + it * TPBP + t;
        if (q < nq) {
            int4 d = d4p[q];
            atomicAdd(&h[d.x >> RSH], 1);
            atomicAdd(&h[d.y >> RSH], 1);
            atomicAdd(&h[d.z >> RSH], 1);
            atomicAdd(&h[d.w >> RSH], 1);
        }
    }
    __syncthreads();
    for (int c = t; c < C; c += TPBP) {           // reserve chunk per range
        int v = h[c];
        if (v) h[c] = (c << CSH) + atomicAdd(&gcur[c], v);   // absolute cursor
    }
    __syncthreads();
#pragma unroll
    for (int it = 0; it < EPB / (4 * TPBP); it++) {  // pass 2: chunked place
        int q = qbase + it * TPBP + t;
        if (q < nq) {
            int4 s = s4p[q];
            int4 d = d4p[q];
            int c0 = d.x >> RSH, c1 = d.y >> RSH, c2 = d.z >> RSH, c3 = d.w >> RSH;
            int p0 = atomicAdd(&h[c0], 1);
            if (p0 < ((c0 + 1) << CSH))
                gbuf[p0] = ((unsigned)s.x << RSH) | (unsigned)(d.x & (RNG - 1));
            int p1 = atomicAdd(&h[c1], 1);
            if (p1 < ((c1 + 1) << CSH))
                gbuf[p1] = ((unsigned)s.y << RSH) | (unsigned)(d.y & (RNG - 1));
            int p2 = atomicAdd(&h[c2], 1);
            if (p2 < ((c2 + 1) << CSH))
                gbuf[p2] = ((unsigned)s.z << RSH) | (unsigned)(d.z & (RNG - 1));
            int p3 = atomicAdd(&h[c3], 1);
            if (p3 < ((c3 + 1) << CSH))
                gbuf[p3] = ((unsigned)s.w << RSH) | (unsigned)(d.w & (RNG - 1));
        }
    }
}

// per-range node-sort (via LDS elist) -> bucketS region + packed CSR + hsx
__global__ __launch_bounds__(TPBS) void
k_sort2(const unsigned* __restrict__ gbuf, const int* __restrict__ gcur,
        const float* __restrict__ x,
        int* __restrict__ bucketS, unsigned* __restrict__ pack,
        __half2* __restrict__ hsx, int N, int C) {
    __shared__ unsigned elist[CAPR];              // 16 KiB
    __shared__ int cnt[RNG];
    __shared__ int offs[RNG];
    __shared__ int cur[RNG];
    __shared__ float sdi[RNG];
    int t = threadIdx.x, r = blockIdx.x;
    if (t < RNG) cnt[t] = 0;
    __syncthreads();
    int m = min(gcur[r], CAPR);
    const unsigned* src = gbuf + ((size_t)r << CSH);
    for (int i = t; i < m; i += TPBS) {           // single global read of region
        unsigned p = src[i];
        elist[i] = p;
        atomicAdd(&cnt[p & (RNG - 1)], 1);
    }
    __syncthreads();
    if (t < RNG) offs[t] = cnt[t];
    __syncthreads();
    for (int off = 1; off < RNG; off <<= 1) {     // Hillis-Steele inclusive scan
        int v = 0;
        if (t < RNG && t >= off) v = offs[t - off];
        __syncthreads();
        if (t < RNG) offs[t] += v;
        __syncthreads();
    }
    if (t < RNG) {
        int ex = offs[t] - cnt[t];                // exclusive
        cur[t] = ex;
        sdi[t] = rsqrtf((float)cnt[t] + 1.0f);    // +1 self-loop
        int n = r * RNG + t;
        if (n < N) pack[n] = ((unsigned)ex << 16) | (unsigned)cnt[t];
    }
    __syncthreads();
    int rbase = r << CSH;
    for (int i = t; i < m; i += TPBS) {
        unsigned p = elist[i];
        int pos = rbase + atomicAdd(&cur[p & (RNG - 1)], 1);
        bucketS[pos] = (int)(p >> RSH);
    }
    // fused: hsx[n][:] = fp16(dinv[n] * x[n][:]) — 128 nodes x 8 half2
    for (int idx = t; idx < RNG * 8; idx += TPBS) {
        int ln = idx >> 3, f2 = idx & 7;
        int n = r * RNG + ln;
        if (n < N) {
            float2 xv = ((const float2*)x)[(size_t)n * 8 + f2];
            float dn = sdi[ln];
            hsx[(size_t)n * 8 + f2] = __floats2half2_rn(xv.x * dn, xv.y * dn);
        }
    }
}

// layer 1 + projection: nodes-in-lane gather (16 nodes/wave), register weights
__global__ void k_l1f(const int* __restrict__ bucketS, const unsigned* __restrict__ pack,
                      const uint2* __restrict__ hsx, const float* __restrict__ W1,
                      const float* __restrict__ b1, const float* __restrict__ Wf,
                      __half2* __restrict__ z, int N) {
    __shared__ __align__(16) float agg[4][16][16];   // [wave][node][feat]
    __shared__ __align__(16) float vrow[4][64];
    int t = threadIdx.x, wid = t >> 6, lane = t & 63;
    int part = lane >> 4, o = lane & 15;
    // register weights: lane j holds W1[:,j]; lane (part,o) holds Wf[part*16+j][o]
    float w1c[16], wfc[16];
#pragma unroll
    for (int k = 0; k < 16; k++) w1c[k] = W1[k * 64 + lane];
#pragma unroll
    for (int j = 0; j < 16; j++) wfc[j] = Wf[(part * 16 + j) * 16 + o];
    float b1v = b1[lane];
    int nodeG = (blockIdx.x * 4 + wid) * 16;      // 16 nodes per wave
    // gather: lane (n4,q) owns node nodeG+n4, slot q (8B of the 32B row)
    int n4 = lane >> 2, q = lane & 3;
    int n = nodeG + n4;
    bool valid = n < N;
    int base = 0, d = 0;
    if (valid) {
        unsigned p = pack[n];
        base = ((n >> RSH) << CSH) + (int)(p >> 16);
        d = (int)(p & 0xFFFF);
    }
    float a[4] = {0.f, 0.f, 0.f, 0.f};
    if (valid) acc4(a, hsx[(size_t)n * 4 + q]);   // self-loop
    int k = 0;
    for (; k + 1 < d; k += 2) {                   // 2 chains/lane, 128/wave
        int s0 = bucketS[base + k];
        int s1 = bucketS[base + k + 1];
        uint2 u0 = hsx[(size_t)s0 * 4 + q];
        uint2 u1 = hsx[(size_t)s1 * 4 + q];
        acc4(a, u0);
        acc4(a, u1);
    }
    if (k < d) acc4(a, hsx[(size_t)bucketS[base + k] * 4 + q]);
    *(float4*)&agg[wid][n4][q * 4] = make_float4(a[0], a[1], a[2], a[3]);
    // epilogue: 16 nodes batched; agg/vrow same-wave LDS roundtrips (b128)
    const float4* avp = (const float4*)agg[wid];
    const float4* vrp = (const float4*)vrow[wid];
#pragma unroll 4
    for (int nn = 0; nn < 16; nn++) {
        int node = nodeG + nn;
        if (node >= N) break;                     // wave-uniform
        float dn = rsqrtf((float)__shfl(d, nn * 4) + 1.0f);  // deg from owner lane
        float4 A0 = avp[nn * 4 + 0], A1 = avp[nn * 4 + 1];
        float4 A2 = avp[nn * 4 + 2], A3 = avp[nn * 4 + 3];
        float av[16] = {A0.x, A0.y, A0.z, A0.w, A1.x, A1.y, A1.z, A1.w,
                        A2.x, A2.y, A2.z, A2.w, A3.x, A3.y, A3.z, A3.w};
        float v = 0.f;
#pragma unroll
        for (int kk = 0; kk < 16; kk++) v += av[kk] * w1c[kk];
        v = fmaxf(dn * v + b1v, 0.f) * dn;        // lane j holds v_j
        vrow[wid][lane] = v;
        float4 V0 = vrp[part * 4 + 0], V1 = vrp[part * 4 + 1];
        float4 V2 = vrp[part * 4 + 2], V3 = vrp[part * 4 + 3];
        float vv[16] = {V0.x, V0.y, V0.z, V0.w, V1.x, V1.y, V1.z, V1.w,
                        V2.x, V2.y, V2.z, V2.w, V3.x, V3.y, V3.z, V3.w};
        float s = 0.f;
#pragma unroll
        for (int j = 0; j < 16; j++) s += vv[j] * wfc[j];
        s += __shfl_xor(s, 16);
        s += __shfl_xor(s, 32);                   // all lanes: z_o, o=lane&15
        float pv = __shfl(s, lane | 1);
        if (part == 0 && !(lane & 1))
            z[(size_t)node * 8 + (o >> 1)] = __floats2half2_rn(s, pv);
    }
}

// layer 2 aggregation of z + bias: pure nodes-in-lane gather, zero DS ops
__global__ void k_l3(const int* __restrict__ bucketS, const unsigned* __restrict__ pack,
                     const uint2* __restrict__ z, const float* __restrict__ bfv,
                     float* __restrict__ out, int N) {
    int t = threadIdx.x, wid = t >> 6, lane = t & 63;
    int n4 = lane >> 2, q = lane & 3;
    int n = (blockIdx.x * 4 + wid) * 16 + n4;
    if (n >= N) return;
    float4 bq = ((const float4*)bfv)[q];
    unsigned p = pack[n];
    int base = ((n >> RSH) << CSH) + (int)(p >> 16);
    int d = (int)(p & 0xFFFF);
    float a[4] = {0.f, 0.f, 0.f, 0.f};
    acc4(a, z[(size_t)n * 4 + q]);                // self-loop
    int k = 0;
    for (; k + 1 < d; k += 2) {
        int s0 = bucketS[base + k];
        int s1 = bucketS[base + k + 1];
        uint2 u0 = z[(size_t)s0 * 4 + q];
        uint2 u1 = z[(size_t)s1 * 4 + q];
        acc4(a, u0);
        acc4(a, u1);
    }
    if (k < d) acc4(a, z[(size_t)bucketS[base + k] * 4 + q]);
    float dn = rsqrtf((float)d + 1.0f);
    float4 r;
    r.x = dn * a[0] + bq.x;
    r.y = dn * a[1] + bq.y;
    r.z = dn * a[2] + bq.z;
    r.w = dn * a[3] + bq.w;
    ((float4*)out)[(size_t)n * 4 + q] = r;        // fully coalesced
}

extern "C" void kernel_launch(void* const* d_in, const int* in_sizes, int n_in,
                              void* d_out, int out_size, void* d_ws, size_t ws_size,
                              hipStream_t stream) {
    const float* x  = (const float*)d_in[0];
    const int*   ei = (const int*)d_in[1];
    const float* W1 = (const float*)d_in[2];
    const float* b1 = (const float*)d_in[3];
    const float* W2 = (const float*)d_in[4];
    const float* b2 = (const float*)d_in[5];
    const float* WL = (const float*)d_in[6];
    const float* bL = (const float*)d_in[7];
    float* out = (float*)d_out;

    const int N  = in_sizes[0] / 16;       // 100000
    const int E  = in_sizes[1] / 2;        // 1600000
    const int C  = (N + RNG - 1) >> RSH;   // 782 ranges
    const int NB = (E + EPB - 1) / EPB;    // 196 place blocks

    // ws ints: gbuf[C*CAPR] | bucketS[C*CAPR] | gcur[C] | pack[N] | pad
    //    then: Wf[1024] f32 | bf[16] | pad16B | hsx[8N] half2 | z[8N] half2
    int* wsi        = (int*)d_ws;
    unsigned* gbuf  = (unsigned*)wsi;
    int* bucketS    = wsi + ((size_t)C << CSH);
    int* gcur       = bucketS + ((size_t)C << CSH);
    unsigned* pack  = (unsigned*)(gcur + C);
    size_t off      = ((size_t)C << (CSH + 1)) + C + N;
    off = (off + 3) & ~(size_t)3;
    float* Wf    = (float*)(wsi + off);
    float* bf    = Wf + 1024;
    off = off + 1024 + 16;
    off = (off + 3) & ~(size_t)3;                 // 16B-align fp16 section
    __half2* hsx = (__half2*)(wsi + off);         // 8N half2
    __half2* z   = (__half2*)(wsi + off + (size_t)8 * N);

    // zero reservation cursors (3 KB) — replaces the k_wfuse dispatch
    hipMemsetAsync(gcur, 0, (size_t)C * 4, stream);

    // ---- chunked placement into per-range regions + fused Wf/bf block ----
    k_place<<<NB + 1, TPBP, 0, stream>>>(ei, gcur, gbuf, W2, WL, b2, bL, Wf, bf, E, C, NB);

    // ---- per-range node sort -> region CSR + pack + fp16 hsx ----
    k_sort2<<<C, TPBS, 0, stream>>>(gbuf, gcur, x, bucketS, pack, hsx, N, C);

    // ---- layer 1 + projection -> z fp16 [N,16] ----
    const int NBLK = (N + 63) / 64;               // 64 nodes per block (16/wave)
    k_l1f<<<NBLK, TPB, 0, stream>>>(bucketS, pack, (const uint2*)hsx, W1, b1, Wf, z, N);

    // ---- layer 2 aggregation + bias -> out ----
    k_l3<<<NBLK, TPB, 0, stream>>>(bucketS, pack, (const uint2*)z, bf, out, N);
}